// Round 2
// baseline (88060.242 us; speedup 1.0000x reference)
//
#include <hip/hip_runtime.h>

typedef float f32x4 __attribute__((ext_vector_type(4)));
typedef short s16x8 __attribute__((ext_vector_type(8)));

#define MINI(a,b) ((a)<(b)?(a):(b))
#define MAXI(a,b) ((a)>(b)?(a):(b))

static __device__ __forceinline__ float bf2f(unsigned short u){
  union { unsigned int i; float f; } x; x.i = ((unsigned int)u) << 16; return x.f;
}
static __device__ __forceinline__ unsigned short f2bf(float f){
  union { float f; unsigned int i; } x; x.f = f;
  return (unsigned short)((x.i + 0x7fffu + ((x.i >> 16) & 1u)) >> 16);
}
static __device__ __forceinline__ float sigm(float x){ return 1.f / (1.f + __expf(-x)); }
static __device__ __forceinline__ float tanhf_(float x){ return 1.f - 2.f / (1.f + __expf(2.f * x)); }

// ---------------------------------------------------------------------------
// K1: fold Wq into key projection.  Bmat[k][n] (bf16): n<256 -> scale*Wk@Wq^T,
// n>=256 -> Wv.  bvec[n]: n<256 -> scale*bk@Wq^T, else bv.  wkb[k]=scale*Wk@bq,
// cb0 = scale*bk.bq
// ---------------------------------------------------------------------------
__global__ void k_prepw(const float* Wk, const float* Wq, const float* Wv,
                        const float* bk, const float* bq, const float* bv,
                        unsigned short* Bm, float* bvec, float* wkb, float* cb0){
  const int k = blockIdx.x;     // 512 blocks
  const int t = threadIdx.x;    // 256 threads
  const float scale = 0.0625f;  // 1/sqrt(256)
  float acc = 0.f;
  for (int p = 0; p < 256; p++) acc += Wk[k*256+p] * Wq[t*256+p];
  Bm[(size_t)k*512 + t]       = f2bf(acc * scale);
  Bm[(size_t)k*512 + 256 + t] = f2bf(Wv[k*256+t]);
  __shared__ float red[256];
  red[t] = Wk[k*256+t] * bq[t];
  __syncthreads();
  for (int o = 128; o > 0; o >>= 1){ if (t < o) red[t] += red[t+o]; __syncthreads(); }
  if (t == 0) wkb[k] = red[0] * scale;
  if (k == 0){
    float a2 = 0.f;
    for (int p = 0; p < 256; p++) a2 += bk[p] * Wq[t*256+p];
    bvec[t] = a2 * scale;
    bvec[256+t] = bv[t];
    __syncthreads();
    red[t] = bk[t] * bq[t];
    __syncthreads();
    for (int o = 128; o > 0; o >>= 1){ if (t < o) red[t] += red[t+o]; __syncthreads(); }
    if (t == 0) *cb0 = red[0] * scale;
  }
}

// ---------------------------------------------------------------------------
// K2: keybias[m] = scale * (key_proj[m] . bq) = enc[m] . wkb + cb0
// ---------------------------------------------------------------------------
__global__ void k_keybias(const float* enc, const float* wkb, const float* cb0,
                          float* keybias){
  const int m = blockIdx.x*8 + (threadIdx.x >> 6);
  const int lane = threadIdx.x & 63;
  float p = 0.f;
  #pragma unroll
  for (int j = 0; j < 8; j++){ int k = lane + 64*j; p += enc[(size_t)m*512 + k] * wkb[k]; }
  #pragma unroll
  for (int o = 1; o < 64; o <<= 1) p += __shfl_xor(p, o, 64);
  if (lane == 0) keybias[m] = p + *cb0;
}

// ---------------------------------------------------------------------------
// K3: state init.  ctx0 = key_proj[:,0,:] (exact f32), l=1, SOS embedding,
// zero h1/c1/h2/c2, zero barrier counter.
// ---------------------------------------------------------------------------
__global__ void k_init(const float* enc, const float* Wk, const float* bk,
                       const float* embW, float* xh, float* ctxacc, float* lacc,
                       float* c1, float* c2, float* h2buf, unsigned int* ctr){
  const int b = blockIdx.x, t = threadIdx.x;  // 64 x 256
  float acc = bk[t];
  const float* er = enc + (size_t)b*800*512;
  for (int k = 0; k < 512; k++) acc += er[k] * Wk[(size_t)k*256 + t];
  ctxacc[b*256 + t] = acc;
  if (t == 0) lacc[b] = 1.f;
  for (int e = t; e < 512; e += 256) xh[b*1280 + e] = embW[e];        // SOS row (tok 0)
  xh[b*1280 + 512 + t] = 0.f;                                        // unused slice
  for (int e = t; e < 512; e += 256) xh[b*1280 + 768 + e] = 0.f;     // h1 = 0
  for (int e = t; e < 512; e += 256) c1[b*512 + e] = 0.f;
  c2[b*256 + t] = 0.f;
  h2buf[b*256 + t] = 0.f;
  if (b == 0 && t == 0) *ctr = 0u;
}

// ---------------------------------------------------------------------------
// K4: MFMA bf16 GEMM  kv[m][n] = bf16( enc[m]@Bmat[:,n] + bvec[n] )
// M=51200, N=512, K=512; 64x64 tile, 4 waves, 16x16x32 bf16.
// ---------------------------------------------------------------------------
__global__ __launch_bounds__(256) void k_gemm(const float* enc, const unsigned short* Bm,
                                              const float* bvec, unsigned short* kv){
  __shared__ unsigned short Al[64][40];
  __shared__ unsigned short Bl[64][40];
  const int tid = threadIdx.x, w = tid >> 6, lane = tid & 63;
  const int M0 = (blockIdx.x >> 3) * 64;
  const int N0 = (blockIdx.x & 7) * 64;
  f32x4 acc[4] = {};
  const int mrow = w*16 + (lane & 15);
  const int koff = (lane >> 4) * 8;
  for (int k0 = 0; k0 < 512; k0 += 32){
    #pragma unroll
    for (int it = 0; it < 2; it++){
      int row = (tid >> 3) + it*32, kq = (tid & 7) * 4;
      float4 v = *(const float4*)(enc + (size_t)(M0+row)*512 + k0 + kq);
      Al[row][kq+0] = f2bf(v.x); Al[row][kq+1] = f2bf(v.y);
      Al[row][kq+2] = f2bf(v.z); Al[row][kq+3] = f2bf(v.w);
    }
    #pragma unroll
    for (int i = 0; i < 8; i++){
      int flat = tid*8 + i, kk = flat >> 6, n = flat & 63;
      Bl[n][kk] = Bm[(size_t)(k0+kk)*512 + N0 + n];
    }
    __syncthreads();
    s16x8 a = *(const s16x8*)&Al[mrow][koff];
    #pragma unroll
    for (int i = 0; i < 4; i++){
      s16x8 bb = *(const s16x8*)&Bl[i*16 + (lane & 15)][koff];
      acc[i] = __builtin_amdgcn_mfma_f32_16x16x32_bf16(a, bb, acc[i], 0, 0, 0);
    }
    __syncthreads();
  }
  #pragma unroll
  for (int i = 0; i < 4; i++){
    int n = N0 + i*16 + (lane & 15);
    float bb = bvec[n];
    #pragma unroll
    for (int r = 0; r < 4; r++){
      int m = M0 + w*16 + (lane >> 4)*4 + r;
      kv[(size_t)m*512 + n] = f2bf(acc[i][r] + bb);
    }
  }
}

// ---------------------------------------------------------------------------
// Decode: persistent kernel, 256 blocks x 512 threads, 3 grid barriers/step.
// ---------------------------------------------------------------------------
static __device__ __forceinline__ void gbar(unsigned int* ctr, unsigned int* gen){
  __threadfence();
  __syncthreads();
  if (threadIdx.x == 0){
    *gen += 256u;
    __hip_atomic_fetch_add(ctr, 1u, __ATOMIC_ACQ_REL, __HIP_MEMORY_SCOPE_AGENT);
    while (__hip_atomic_load(ctr, __ATOMIC_ACQUIRE, __HIP_MEMORY_SCOPE_AGENT) < *gen)
      __builtin_amdgcn_s_sleep(2);
  }
  __syncthreads();
  __threadfence();  // acquire insurance for all waves (L1 invalidate)
}

static __device__ __forceinline__ void fma4x8(const float* xp, const float* wrow, float* acc){
  float4 xv = *(const float4*)xp;
  #pragma unroll
  for (int j = 0; j < 4; j++){
    float xs = (j==0) ? xv.x : (j==1) ? xv.y : (j==2) ? xv.z : xv.w;
    float4 wa = *(const float4*)(wrow + j*8);
    float4 wb = *(const float4*)(wrow + j*8 + 4);
    acc[0] += xs*wa.x; acc[1] += xs*wa.y; acc[2] += xs*wa.z; acc[3] += xs*wa.w;
    acc[4] += xs*wb.x; acc[5] += xs*wb.y; acc[6] += xs*wb.z; acc[7] += xs*wb.w;
  }
}
static __device__ __forceinline__ void fma4x4(const float* xp, const float* wrow, float* acc){
  float4 xv = *(const float4*)xp;
  #pragma unroll
  for (int j = 0; j < 4; j++){
    float xs = (j==0) ? xv.x : (j==1) ? xv.y : (j==2) ? xv.z : xv.w;
    float4 wv = *(const float4*)(wrow + j*4);
    acc[0] += xs*wv.x; acc[1] += xs*wv.y; acc[2] += xs*wv.z; acc[3] += xs*wv.w;
  }
}

__global__ __launch_bounds__(512) void k_decode(
    const float* W_ih1, const float* b_ih1, const float* W_hh1, const float* b_hh1,
    const float* W_ih2, const float* b_ih2, const float* W_hh2, const float* b_hh2,
    const float* embW, const float* char_b, const int* lens, const int* y,
    const unsigned short* kv, const float* keybias,
    float* xh, float* ctxacc, float* lacc, float* h2buf, float* c1, float* c2,
    float* esc, unsigned int* ctr, float* out)
{
  __shared__ float W1s[1280][8];   // K-major, 8 gate1 cols of this block
  __shared__ float W2s[768][4];    // K-major, 4 gate2 cols of this block
  __shared__ float b1s[8];
  __shared__ float b2s[4];
  __shared__ float embrow[512];
  __shared__ float chb;
  __shared__ float redA[8][8][64]; // per-kslice partials / P3 pctx scratch
  __shared__ float g1s[8][64];     // final gates / logits partials
  __shared__ float lred[8];

  const int bi = blockIdx.x;
  const int tid = threadIdx.x;
  const int w = tid >> 6;
  const int lane = tid & 63;

  // persistent weight load (one time)
  for (int idx = tid; idx < 1280*8; idx += 512){
    int k = idx >> 3, c = idx & 7;
    int col = ((c >> 1) << 9) + 2*bi + (c & 1);
    W1s[k][c] = (k < 768) ? W_ih1[(size_t)k*2048 + col] : W_hh1[(size_t)(k-768)*2048 + col];
  }
  for (int idx = tid; idx < 768*4; idx += 512){
    int k = idx >> 2, c = idx & 3;
    int col = (c << 8) + bi;
    W2s[k][c] = (k < 512) ? W_ih2[(size_t)k*1024 + col] : W_hh2[(size_t)(k-512)*1024 + col];
  }
  if (tid < 8){ int col = ((tid >> 1) << 9) + 2*bi + (tid & 1); b1s[tid] = b_ih1[col] + b_hh1[col]; }
  if (tid >= 8 && tid < 12){ int c = tid-8; int col = (c << 8) + bi; b2s[c] = b_ih2[col] + b_hh2[col]; }
  if (bi < 30){
    if (tid < 512) embrow[tid] = embW[bi*512 + tid];
    if (tid == 0) chb = char_b[bi];
  }
  __syncthreads();

  unsigned int gen = 0;
  const int myb = bi & 63;   // attention batch
  const int sc  = bi >> 6;   // attention s-phase (mod 4)
  const int mylen = lens[myb];

  float* preds = out;            // [64][250][30]
  float* plot  = out + 480000;   // [800][250]

  for (int t = 0; t <= 250; ++t){
    const int p  = t & 1;
    const int np = 1 - p;
    const float* xh_p  = xh + p*(64*1280);
    float*       xh_np = xh + np*(64*1280);
    const float* ca_p  = ctxacc + p*(64*256);
    float*       ca_np = ctxacc + np*(64*256);
    const float* la_p  = lacc + p*64;
    float*       la_np = lacc + np*64;
    const float* h2_p  = h2buf + p*(64*256);
    float*       h2_np = h2buf + np*(64*256);

    // ---------------- Phase 1: gates1 + LSTM1 ----------------
    if (t < 250){
      float acc[8]  = {0.f,0.f,0.f,0.f,0.f,0.f,0.f,0.f};
      float accB[8] = {0.f,0.f,0.f,0.f,0.f,0.f,0.f,0.f};
      const int b = lane;
      const float* xrow = xh_p + b*1280;
      const float* crow = ca_p + b*256 - 512;
      const int k0 = w*160, k1 = k0 + 160;
      const int a1 = MINI(k1, 512);
      for (int k = k0; k < a1; k += 4)  fma4x8(xrow + k, &W1s[k][0], acc);
      const int bb0 = MAXI(k0, 512), bb1 = MINI(k1, 768);
      for (int k = bb0; k < bb1; k += 4) fma4x8(crow + k, &W1s[k][0], accB);
      const int cc0 = MAXI(k0, 768);
      for (int k = cc0; k < k1; k += 4) fma4x8(xrow + k, &W1s[k][0], acc);
      const float rl = 1.f / la_p[b];
      #pragma unroll
      for (int c = 0; c < 8; c++) redA[w][c][b] = acc[c] + accB[c]*rl;
    }
    __syncthreads();
    if (t < 250){
      { // reduce k-slices -> gates
        int c = tid >> 6, b = tid & 63;
        float g = b1s[c];
        #pragma unroll
        for (int ww = 0; ww < 8; ww++) g += redA[ww][c][b];
        g1s[c][b] = g;
      }
      __syncthreads();
      if (w < 2){ // LSTM1 cell update for jj = 2*bi + w
        int jj = 2*bi + w; int b = lane;
        float gi = g1s[0+w][b], gf = g1s[2+w][b], gg = g1s[4+w][b], go = g1s[6+w][b];
        float cold = c1[b*512 + jj];
        float cn = sigm(gf)*cold + sigm(gi)*tanhf_(gg);
        c1[b*512 + jj] = cn;
        xh_np[b*1280 + 768 + jj] = sigm(go)*tanhf_(cn);
      }
    }
    __syncthreads();
    // ---------------- logits / attention-plot for step t-1 ----------------
    if (t > 0){
      if (bi < 30){
        int b3 = tid & 63, ch = tid >> 6;
        float part;
        if (ch < 4){
          const float* hr = h2_p + b3*256 + ch*64;
          const float* er = &embrow[ch*64];
          float pc = 0.f;
          for (int e = 0; e < 64; e += 4){
            float4 a = *(const float4*)(hr+e); float4 bb = *(const float4*)(er+e);
            pc += a.x*bb.x + a.y*bb.y + a.z*bb.z + a.w*bb.w;
          }
          part = pc;
        } else {
          const float* cr = ca_p + b3*256 + (ch-4)*64;
          const float* er = &embrow[256 + (ch-4)*64];
          float pc = 0.f;
          for (int e = 0; e < 64; e += 4){
            float4 a = *(const float4*)(cr+e); float4 bb = *(const float4*)(er+e);
            pc += a.x*bb.x + a.y*bb.y + a.z*bb.z + a.w*bb.w;
          }
          part = pc * (1.f / la_p[b3]);
        }
        g1s[ch][b3] = part;
      }
      __syncthreads();
      if (bi < 30 && tid < 64){
        float s2 = chb;
        #pragma unroll
        for (int ch = 0; ch < 8; ch++) s2 += g1s[ch][tid];
        preds[tid*7500 + (t-1)*30 + bi] = s2;
      } else if (bi >= 30 && bi < 62 && tid < 25){
        int s3 = (bi-30)*25 + tid;
        plot[(size_t)s3*250 + (t-1)] = esc[s3] * (1.f / la_p[0]);
      }
    }
    if (t == 250) break;
    gbar(ctr, &gen);  // SYNC1: h1 ready

    // ---------------- Phase 2: gates2 + LSTM2 + housekeeping ----------------
    {
      float acc2[4] = {0.f,0.f,0.f,0.f};
      const int b = lane;
      const float* h1r = xh_np + b*1280 + 768;
      const float* h2r = h2_p + b*256 - 512;
      const int k0 = w*96, k1 = k0 + 96;
      const int a1 = MINI(k1, 512);
      for (int k = k0; k < a1; k += 4) fma4x4(h1r + k, &W2s[k][0], acc2);
      const int bb0 = MAXI(k0, 512);
      for (int k = bb0; k < k1; k += 4) fma4x4(h2r + k, &W2s[k][0], acc2);
      #pragma unroll
      for (int c = 0; c < 4; c++) redA[w][c][b] = acc2[c];
    }
    __syncthreads();
    if (tid < 256){
      int c = tid >> 6, b = tid & 63;
      float g = b2s[c];
      #pragma unroll
      for (int ww = 0; ww < 8; ww++) g += redA[ww][c][b];
      g1s[c][b] = g;
    }
    __syncthreads();
    if (w == 0){
      int b = lane;
      float gi = g1s[0][b], gf = g1s[1][b], gg = g1s[2][b], go = g1s[3][b];
      float cold = c2[b*256 + bi];
      float cn = sigm(gf)*cold + sigm(gi)*tanhf_(gg);
      c2[b*256 + bi] = cn;
      h2_np[b*256 + bi] = sigm(go)*tanhf_(cn);
    }
    // housekeeping for next phase / next step
    if (tid < 64) ca_np[bi*64 + tid] = 0.f;
    if (bi < 64 && tid == 64) la_np[bi] = 0.f;
    if (bi >= 64 && bi < 96 && tid >= 128 && tid < 153) esc[(bi-64)*25 + (tid-128)] = 0.f;
    if (t < 249 && tid >= 256 && tid < 384){
      int tok = y[(bi & 63)*250 + t];
      int e = ((bi >> 6) << 7) + (tid - 256);
      xh_np[(bi & 63)*1280 + e] = embW[(size_t)tok*512 + e];
    }
    gbar(ctr, &gen);  // SYNC2: h2 ready, accumulators zeroed

    // ---------------- Phase 3: attention (online, no max needed) ----------------
    {
      float4 hh = *(const float4*)(h2_np + myb*256 + lane*4);
      float l = 0.f, p0 = 0.f, p1 = 0.f, p2 = 0.f, p3 = 0.f;
      const unsigned short* kvb = kv + (size_t)myb*800*512;
      const float* kbr = keybias + myb*800;
      const bool wr0 = (myb == 0) && (lane == 0);
      for (int s = sc + 4*w; s < mylen; s += 32){
        const unsigned short* row = kvb + (size_t)s*512 + lane*4;
        ushort4 kq = *(const ushort4*)row;
        ushort4 vq = *(const ushort4*)(row + 256);  // FIX: val at col 256+lane*4 (was +512 = next row's key)
        float part = bf2f(kq.x)*hh.x + bf2f(kq.y)*hh.y + bf2f(kq.z)*hh.z + bf2f(kq.w)*hh.w;
        #pragma unroll
        for (int o2 = 1; o2 < 64; o2 <<= 1) part += __shfl_xor(part, o2, 64);
        float e = __expf(part + kbr[s]);
        l += e;
        p0 += e*bf2f(vq.x); p1 += e*bf2f(vq.y); p2 += e*bf2f(vq.z); p3 += e*bf2f(vq.w);
        if (wr0) esc[s] = e;
      }
      float* redf = (float*)redA;  // view [8][512]
      redf[w*512 + lane*4 + 0] = p0; redf[w*512 + lane*4 + 1] = p1;
      redf[w*512 + lane*4 + 2] = p2; redf[w*512 + lane*4 + 3] = p3;
      if (lane == 0) lred[w] = l;
      __syncthreads();
      if (tid < 256){
        float s4 = 0.f;
        #pragma unroll
        for (int ww = 0; ww < 8; ww++) s4 += redf[ww*512 + tid];
        atomicAdd(&ca_np[myb*256 + tid], s4);
      }
      if (tid == 0){
        float ls = 0.f;
        #pragma unroll
        for (int ww = 0; ww < 8; ww++) ls += lred[ww];
        atomicAdd(&la_np[myb], ls);
      }
    }
    gbar(ctr, &gen);  // SYNC3: context accumulated
  }
}

// ---------------------------------------------------------------------------
extern "C" void kernel_launch(void* const* d_in, const int* in_sizes, int n_in,
                              void* d_out, int out_size, void* d_ws, size_t ws_size,
                              hipStream_t stream){
  const float* enc    = (const float*)d_in[0];
  const float* embW   = (const float*)d_in[1];
  const float* W_ih1  = (const float*)d_in[2];
  const float* b_ih1  = (const float*)d_in[3];
  const float* W_hh1  = (const float*)d_in[4];
  const float* b_hh1  = (const float*)d_in[5];
  const float* W_ih2  = (const float*)d_in[6];
  const float* b_ih2  = (const float*)d_in[7];
  const float* W_hh2  = (const float*)d_in[8];
  const float* b_hh2  = (const float*)d_in[9];
  const float* Wk     = (const float*)d_in[10];
  const float* bk     = (const float*)d_in[11];
  const float* Wv     = (const float*)d_in[12];
  const float* bv     = (const float*)d_in[13];
  const float* Wq     = (const float*)d_in[14];
  const float* bq     = (const float*)d_in[15];
  const float* char_b = (const float*)d_in[16];
  const int*   lens   = (const int*)d_in[17];
  const int*   y      = (const int*)d_in[18];

  char* ws = (char*)d_ws;
  unsigned short* kvp  = (unsigned short*)(ws + 0);          // 52,428,800 B
  float* keybias       = (float*)(ws + 52428800);            //    204,800
  unsigned short* Bmat = (unsigned short*)(ws + 52633600);   //    524,288
  float* bvec          = (float*)(ws + 53157888);            //      2,048
  float* wkb           = (float*)(ws + 53159936);            //      2,048
  float* cb0           = (float*)(ws + 53161984);            //      1,024
  float* xh            = (float*)(ws + 53163008);            //    655,360
  float* ctxacc        = (float*)(ws + 53818368);            //    131,072
  float* lacc          = (float*)(ws + 53949440);            //      1,024
  float* h2buf         = (float*)(ws + 53950464);            //    131,072
  float* c1            = (float*)(ws + 54081536);            //    131,072
  float* c2            = (float*)(ws + 54212608);            //     65,536
  float* esc           = (float*)(ws + 54278144);            //      4,096
  unsigned int* ctr    = (unsigned int*)(ws + 54282240);     //      1,024
  float* out = (float*)d_out;

  k_prepw<<<512, 256, 0, stream>>>(Wk, Wq, Wv, bk, bq, bv, Bmat, bvec, wkb, cb0);
  k_keybias<<<6400, 512, 0, stream>>>(enc, wkb, cb0, keybias);
  k_init<<<64, 256, 0, stream>>>(enc, Wk, bk, embW, xh, ctxacc, lacc, c1, c2, h2buf, ctr);
  k_gemm<<<6400, 256, 0, stream>>>(enc, Bmat, bvec, kvp);
  k_decode<<<256, 512, 0, stream>>>(W_ih1, b_ih1, W_hh1, b_hh1, W_ih2, b_ih2, W_hh2, b_hh2,
                                    embW, char_b, lens, y, kvp, keybias,
                                    xh, ctxacc, lacc, h2buf, c1, c2, esc, ctr, out);
}

// Round 3
// 31060.733 us; speedup vs baseline: 2.8351x; 2.8351x over previous
//
#include <hip/hip_runtime.h>

typedef float f32x4 __attribute__((ext_vector_type(4)));
typedef short s16x8 __attribute__((ext_vector_type(8)));

#define MINI(a,b) ((a)<(b)?(a):(b))
#define MAXI(a,b) ((a)>(b)?(a):(b))

static __device__ __forceinline__ float bf2f(unsigned short u){
  union { unsigned int i; float f; } x; x.i = ((unsigned int)u) << 16; return x.f;
}
static __device__ __forceinline__ unsigned short f2bf(float f){
  union { float f; unsigned int i; } x; x.f = f;
  return (unsigned short)((x.i + 0x7fffu + ((x.i >> 16) & 1u)) >> 16);
}
static __device__ __forceinline__ float sigm(float x){ return 1.f / (1.f + __expf(-x)); }
static __device__ __forceinline__ float tanhf_(float x){ return 1.f - 2.f / (1.f + __expf(2.f * x)); }

// ---------------------------------------------------------------------------
// K1: fold Wq into key projection.  Bmat[k][n] (bf16): n<256 -> scale*Wk@Wq^T,
// n>=256 -> Wv.  bvec[n]: n<256 -> scale*bk@Wq^T, else bv.  wkb[k]=scale*Wk@bq,
// cb0 = scale*bk.bq
// ---------------------------------------------------------------------------
__global__ void k_prepw(const float* Wk, const float* Wq, const float* Wv,
                        const float* bk, const float* bq, const float* bv,
                        unsigned short* Bm, float* bvec, float* wkb, float* cb0){
  const int k = blockIdx.x;     // 512 blocks
  const int t = threadIdx.x;    // 256 threads
  const float scale = 0.0625f;  // 1/sqrt(256)
  float acc = 0.f;
  for (int p = 0; p < 256; p++) acc += Wk[k*256+p] * Wq[t*256+p];
  Bm[(size_t)k*512 + t]       = f2bf(acc * scale);
  Bm[(size_t)k*512 + 256 + t] = f2bf(Wv[k*256+t]);
  __shared__ float red[256];
  red[t] = Wk[k*256+t] * bq[t];
  __syncthreads();
  for (int o = 128; o > 0; o >>= 1){ if (t < o) red[t] += red[t+o]; __syncthreads(); }
  if (t == 0) wkb[k] = red[0] * scale;
  if (k == 0){
    float a2 = 0.f;
    for (int p = 0; p < 256; p++) a2 += bk[p] * Wq[t*256+p];
    bvec[t] = a2 * scale;
    bvec[256+t] = bv[t];
    __syncthreads();
    red[t] = bk[t] * bq[t];
    __syncthreads();
    for (int o = 128; o > 0; o >>= 1){ if (t < o) red[t] += red[t+o]; __syncthreads(); }
    if (t == 0) *cb0 = red[0] * scale;
  }
}

// ---------------------------------------------------------------------------
// K2: keybias[m] = scale * (key_proj[m] . bq) = enc[m] . wkb + cb0
// ---------------------------------------------------------------------------
__global__ void k_keybias(const float* enc, const float* wkb, const float* cb0,
                          float* keybias){
  const int m = blockIdx.x*8 + (threadIdx.x >> 6);
  const int lane = threadIdx.x & 63;
  float p = 0.f;
  #pragma unroll
  for (int j = 0; j < 8; j++){ int k = lane + 64*j; p += enc[(size_t)m*512 + k] * wkb[k]; }
  #pragma unroll
  for (int o = 1; o < 64; o <<= 1) p += __shfl_xor(p, o, 64);
  if (lane == 0) keybias[m] = p + *cb0;
}

// ---------------------------------------------------------------------------
// K3: state init.  ctx0 = key_proj[:,0,:] (exact f32), l=1, SOS embedding,
// zero h1/c1/h2/c2, zero barrier counters.
// ---------------------------------------------------------------------------
__global__ void k_init(const float* enc, const float* Wk, const float* bk,
                       const float* embW, float* xh, float* ctxacc, float* lacc,
                       float* c1, float* c2, float* h2buf, unsigned int* ctr){
  const int b = blockIdx.x, t = threadIdx.x;  // 64 x 256
  float acc = bk[t];
  const float* er = enc + (size_t)b*800*512;
  for (int k = 0; k < 512; k++) acc += er[k] * Wk[(size_t)k*256 + t];
  ctxacc[b*256 + t] = acc;
  if (t == 0) lacc[b] = 1.f;
  for (int e = t; e < 512; e += 256) xh[b*1280 + e] = embW[e];        // SOS row (tok 0)
  xh[b*1280 + 512 + t] = 0.f;                                        // unused slice
  for (int e = t; e < 512; e += 256) xh[b*1280 + 768 + e] = 0.f;     // h1 = 0
  for (int e = t; e < 512; e += 256) c1[b*512 + e] = 0.f;
  c2[b*256 + t] = 0.f;
  h2buf[b*256 + t] = 0.f;
  if (b == 0) ctr[t] = 0u;   // zero all 256 sub-counter slots
}

// ---------------------------------------------------------------------------
// K4: MFMA bf16 GEMM  kv[m][n] = bf16( enc[m]@Bmat[:,n] + bvec[n] )
// M=51200, N=512, K=512; 64x64 tile, 4 waves, 16x16x32 bf16.
// ---------------------------------------------------------------------------
__global__ __launch_bounds__(256) void k_gemm(const float* enc, const unsigned short* Bm,
                                              const float* bvec, unsigned short* kv){
  __shared__ unsigned short Al[64][40];
  __shared__ unsigned short Bl[64][40];
  const int tid = threadIdx.x, w = tid >> 6, lane = tid & 63;
  const int M0 = (blockIdx.x >> 3) * 64;
  const int N0 = (blockIdx.x & 7) * 64;
  f32x4 acc[4] = {};
  const int mrow = w*16 + (lane & 15);
  const int koff = (lane >> 4) * 8;
  for (int k0 = 0; k0 < 512; k0 += 32){
    #pragma unroll
    for (int it = 0; it < 2; it++){
      int row = (tid >> 3) + it*32, kq = (tid & 7) * 4;
      float4 v = *(const float4*)(enc + (size_t)(M0+row)*512 + k0 + kq);
      Al[row][kq+0] = f2bf(v.x); Al[row][kq+1] = f2bf(v.y);
      Al[row][kq+2] = f2bf(v.z); Al[row][kq+3] = f2bf(v.w);
    }
    #pragma unroll
    for (int i = 0; i < 8; i++){
      int flat = tid*8 + i, kk = flat >> 6, n = flat & 63;
      Bl[n][kk] = Bm[(size_t)(k0+kk)*512 + N0 + n];
    }
    __syncthreads();
    s16x8 a = *(const s16x8*)&Al[mrow][koff];
    #pragma unroll
    for (int i = 0; i < 4; i++){
      s16x8 bb = *(const s16x8*)&Bl[i*16 + (lane & 15)][koff];
      acc[i] = __builtin_amdgcn_mfma_f32_16x16x32_bf16(a, bb, acc[i], 0, 0, 0);
    }
    __syncthreads();
  }
  #pragma unroll
  for (int i = 0; i < 4; i++){
    int n = N0 + i*16 + (lane & 15);
    float bb = bvec[n];
    #pragma unroll
    for (int r = 0; r < 4; r++){
      int m = M0 + w*16 + (lane >> 4)*4 + r;
      kv[(size_t)m*512 + n] = f2bf(acc[i][r] + bb);
    }
  }
}

// ---------------------------------------------------------------------------
// Grid barrier: relaxed polls (NO per-poll L2 invalidate), one release on the
// increment (single wbl2), one acquire fence after the wait (single inv).
// 8 cacheline-spaced sub-counters cut same-address atomic serialization.
// Generation safety: counters are monotone; sum>=256k implies all 256 blocks
// incremented for barrier k (induction on first violator).
// ---------------------------------------------------------------------------
static __device__ __forceinline__ void gbar(unsigned int* ctrs, unsigned int* gen){
  __syncthreads();   // all block writes issued & in L2 (L1 write-through)
  if (threadIdx.x == 0){
    *gen += 256u;
    __hip_atomic_fetch_add(&ctrs[(blockIdx.x & 7) * 32], 1u,
                           __ATOMIC_RELEASE, __HIP_MEMORY_SCOPE_AGENT);
    for (;;){
      unsigned int s = 0;
      #pragma unroll
      for (int i = 0; i < 8; i++)
        s += __hip_atomic_load(&ctrs[i * 32], __ATOMIC_RELAXED, __HIP_MEMORY_SCOPE_AGENT);
      if (s >= *gen) break;
      __builtin_amdgcn_s_sleep(2);
    }
  }
  __syncthreads();
  __builtin_amdgcn_fence(__ATOMIC_ACQUIRE, "agent");  // one L1/L2 invalidate
}

static __device__ __forceinline__ void fma4x8(const float* xp, const float* wrow, float* acc){
  float4 xv = *(const float4*)xp;
  #pragma unroll
  for (int j = 0; j < 4; j++){
    float xs = (j==0) ? xv.x : (j==1) ? xv.y : (j==2) ? xv.z : xv.w;
    float4 wa = *(const float4*)(wrow + j*8);
    float4 wb = *(const float4*)(wrow + j*8 + 4);
    acc[0] += xs*wa.x; acc[1] += xs*wa.y; acc[2] += xs*wa.z; acc[3] += xs*wa.w;
    acc[4] += xs*wb.x; acc[5] += xs*wb.y; acc[6] += xs*wb.z; acc[7] += xs*wb.w;
  }
}
static __device__ __forceinline__ void fma4x4(const float* xp, const float* wrow, float* acc){
  float4 xv = *(const float4*)xp;
  #pragma unroll
  for (int j = 0; j < 4; j++){
    float xs = (j==0) ? xv.x : (j==1) ? xv.y : (j==2) ? xv.z : xv.w;
    float4 wv = *(const float4*)(wrow + j*4);
    acc[0] += xs*wv.x; acc[1] += xs*wv.y; acc[2] += xs*wv.z; acc[3] += xs*wv.w;
  }
}

__global__ __launch_bounds__(512) void k_decode(
    const float* W_ih1, const float* b_ih1, const float* W_hh1, const float* b_hh1,
    const float* W_ih2, const float* b_ih2, const float* W_hh2, const float* b_hh2,
    const float* embW, const float* char_b, const int* lens, const int* y,
    const unsigned short* kv, const float* keybias,
    float* xh, float* ctxacc, float* lacc, float* h2buf, float* c1, float* c2,
    float* esc, unsigned int* ctr, float* out)
{
  __shared__ float W1s[1280][8];   // K-major, 8 gate1 cols of this block
  __shared__ float W2s[768][4];    // K-major, 4 gate2 cols of this block
  __shared__ float b1s[8];
  __shared__ float b2s[4];
  __shared__ float embrow[512];
  __shared__ float chb;
  __shared__ float redA[8][8][64]; // per-kslice partials / P3 pctx scratch
  __shared__ float g1s[8][64];     // final gates / logits partials
  __shared__ float lred[8];

  const int bi = blockIdx.x;
  const int tid = threadIdx.x;
  const int w = tid >> 6;
  const int lane = tid & 63;

  // persistent weight load (one time)
  for (int idx = tid; idx < 1280*8; idx += 512){
    int k = idx >> 3, c = idx & 7;
    int col = ((c >> 1) << 9) + 2*bi + (c & 1);
    W1s[k][c] = (k < 768) ? W_ih1[(size_t)k*2048 + col] : W_hh1[(size_t)(k-768)*2048 + col];
  }
  for (int idx = tid; idx < 768*4; idx += 512){
    int k = idx >> 2, c = idx & 3;
    int col = (c << 8) + bi;
    W2s[k][c] = (k < 512) ? W_ih2[(size_t)k*1024 + col] : W_hh2[(size_t)(k-512)*1024 + col];
  }
  if (tid < 8){ int col = ((tid >> 1) << 9) + 2*bi + (tid & 1); b1s[tid] = b_ih1[col] + b_hh1[col]; }
  if (tid >= 8 && tid < 12){ int c = tid-8; int col = (c << 8) + bi; b2s[c] = b_ih2[col] + b_hh2[col]; }
  if (bi < 30){
    if (tid < 512) embrow[tid] = embW[bi*512 + tid];
    if (tid == 0) chb = char_b[bi];
  }
  __syncthreads();

  unsigned int gen = 0;
  const int myb = bi & 63;   // attention batch
  const int sc  = bi >> 6;   // attention s-phase (mod 4)
  const int mylen = lens[myb];

  float* preds = out;            // [64][250][30]
  float* plot  = out + 480000;   // [800][250]

  for (int t = 0; t <= 250; ++t){
    const int p  = t & 1;
    const int np = 1 - p;
    const float* xh_p  = xh + p*(64*1280);
    float*       xh_np = xh + np*(64*1280);
    const float* ca_p  = ctxacc + p*(64*256);
    float*       ca_np = ctxacc + np*(64*256);
    const float* la_p  = lacc + p*64;
    float*       la_np = lacc + np*64;
    const float* h2_p  = h2buf + p*(64*256);
    float*       h2_np = h2buf + np*(64*256);

    // ---------------- Phase 1: gates1 + LSTM1 ----------------
    if (t < 250){
      float acc[8]  = {0.f,0.f,0.f,0.f,0.f,0.f,0.f,0.f};
      float accB[8] = {0.f,0.f,0.f,0.f,0.f,0.f,0.f,0.f};
      const int b = lane;
      const float* xrow = xh_p + b*1280;
      const float* crow = ca_p + b*256 - 512;
      const int k0 = w*160, k1 = k0 + 160;
      const int a1 = MINI(k1, 512);
      for (int k = k0; k < a1; k += 4)  fma4x8(xrow + k, &W1s[k][0], acc);
      const int bb0 = MAXI(k0, 512), bb1 = MINI(k1, 768);
      for (int k = bb0; k < bb1; k += 4) fma4x8(crow + k, &W1s[k][0], accB);
      const int cc0 = MAXI(k0, 768);
      for (int k = cc0; k < k1; k += 4) fma4x8(xrow + k, &W1s[k][0], acc);
      const float rl = 1.f / la_p[b];
      #pragma unroll
      for (int c = 0; c < 8; c++) redA[w][c][b] = acc[c] + accB[c]*rl;
    }
    __syncthreads();
    if (t < 250){
      { // reduce k-slices -> gates
        int c = tid >> 6, b = tid & 63;
        float g = b1s[c];
        #pragma unroll
        for (int ww = 0; ww < 8; ww++) g += redA[ww][c][b];
        g1s[c][b] = g;
      }
      __syncthreads();
      if (w < 2){ // LSTM1 cell update for jj = 2*bi + w
        int jj = 2*bi + w; int b = lane;
        float gi = g1s[0+w][b], gf = g1s[2+w][b], gg = g1s[4+w][b], go = g1s[6+w][b];
        float cold = c1[b*512 + jj];
        float cn = sigm(gf)*cold + sigm(gi)*tanhf_(gg);
        c1[b*512 + jj] = cn;
        xh_np[b*1280 + 768 + jj] = sigm(go)*tanhf_(cn);
      }
    }
    __syncthreads();
    // ---------------- logits / attention-plot for step t-1 ----------------
    if (t > 0){
      if (bi < 30){
        int b3 = tid & 63, ch = tid >> 6;
        float part;
        if (ch < 4){
          const float* hr = h2_p + b3*256 + ch*64;
          const float* er = &embrow[ch*64];
          float pc = 0.f;
          for (int e = 0; e < 64; e += 4){
            float4 a = *(const float4*)(hr+e); float4 bb = *(const float4*)(er+e);
            pc += a.x*bb.x + a.y*bb.y + a.z*bb.z + a.w*bb.w;
          }
          part = pc;
        } else {
          const float* cr = ca_p + b3*256 + (ch-4)*64;
          const float* er = &embrow[256 + (ch-4)*64];
          float pc = 0.f;
          for (int e = 0; e < 64; e += 4){
            float4 a = *(const float4*)(cr+e); float4 bb = *(const float4*)(er+e);
            pc += a.x*bb.x + a.y*bb.y + a.z*bb.z + a.w*bb.w;
          }
          part = pc * (1.f / la_p[b3]);
        }
        g1s[ch][b3] = part;
      }
      __syncthreads();
      if (bi < 30 && tid < 64){
        float s2 = chb;
        #pragma unroll
        for (int ch = 0; ch < 8; ch++) s2 += g1s[ch][tid];
        preds[tid*7500 + (t-1)*30 + bi] = s2;
      } else if (bi >= 30 && bi < 62 && tid < 25){
        int s3 = (bi-30)*25 + tid;
        plot[(size_t)s3*250 + (t-1)] = esc[s3] * (1.f / la_p[0]);
      }
    }
    if (t == 250) break;
    gbar(ctr, &gen);  // SYNC1: h1 ready

    // ---------------- Phase 2: gates2 + LSTM2 + housekeeping ----------------
    {
      float acc2[4] = {0.f,0.f,0.f,0.f};
      const int b = lane;
      const float* h1r = xh_np + b*1280 + 768;
      const float* h2r = h2_p + b*256 - 512;
      const int k0 = w*96, k1 = k0 + 96;
      const int a1 = MINI(k1, 512);
      for (int k = k0; k < a1; k += 4) fma4x4(h1r + k, &W2s[k][0], acc2);
      const int bb0 = MAXI(k0, 512);
      for (int k = bb0; k < k1; k += 4) fma4x4(h2r + k, &W2s[k][0], acc2);
      #pragma unroll
      for (int c = 0; c < 4; c++) redA[w][c][b] = acc2[c];
    }
    __syncthreads();
    if (tid < 256){
      int c = tid >> 6, b = tid & 63;
      float g = b2s[c];
      #pragma unroll
      for (int ww = 0; ww < 8; ww++) g += redA[ww][c][b];
      g1s[c][b] = g;
    }
    __syncthreads();
    if (w == 0){
      int b = lane;
      float gi = g1s[0][b], gf = g1s[1][b], gg = g1s[2][b], go = g1s[3][b];
      float cold = c2[b*256 + bi];
      float cn = sigm(gf)*cold + sigm(gi)*tanhf_(gg);
      c2[b*256 + bi] = cn;
      h2_np[b*256 + bi] = sigm(go)*tanhf_(cn);
    }
    // housekeeping for next phase / next step
    if (tid < 64) ca_np[bi*64 + tid] = 0.f;
    if (bi < 64 && tid == 64) la_np[bi] = 0.f;
    if (bi >= 64 && bi < 96 && tid >= 128 && tid < 153) esc[(bi-64)*25 + (tid-128)] = 0.f;
    if (t < 249 && tid >= 256 && tid < 384){
      int tok = y[(bi & 63)*250 + t];
      int e = ((bi >> 6) << 7) + (tid - 256);
      xh_np[(bi & 63)*1280 + e] = embW[(size_t)tok*512 + e];
    }
    gbar(ctr, &gen);  // SYNC2: h2 ready, accumulators zeroed

    // ---------------- Phase 3: attention (online, no max needed) ----------------
    {
      float4 hh = *(const float4*)(h2_np + myb*256 + lane*4);
      float l = 0.f, p0 = 0.f, p1 = 0.f, p2 = 0.f, p3 = 0.f;
      const unsigned short* kvb = kv + (size_t)myb*800*512;
      const float* kbr = keybias + myb*800;
      const bool wr0 = (myb == 0) && (lane == 0);
      for (int s = sc + 4*w; s < mylen; s += 32){
        const unsigned short* row = kvb + (size_t)s*512 + lane*4;
        ushort4 kq = *(const ushort4*)row;
        ushort4 vq = *(const ushort4*)(row + 256);  // val at col 256+lane*4
        float part = bf2f(kq.x)*hh.x + bf2f(kq.y)*hh.y + bf2f(kq.z)*hh.z + bf2f(kq.w)*hh.w;
        #pragma unroll
        for (int o2 = 1; o2 < 64; o2 <<= 1) part += __shfl_xor(part, o2, 64);
        float e = __expf(part + kbr[s]);
        l += e;
        p0 += e*bf2f(vq.x); p1 += e*bf2f(vq.y); p2 += e*bf2f(vq.z); p3 += e*bf2f(vq.w);
        if (wr0) esc[s] = e;
      }
      float* redf = (float*)redA;  // view [8][512]
      redf[w*512 + lane*4 + 0] = p0; redf[w*512 + lane*4 + 1] = p1;
      redf[w*512 + lane*4 + 2] = p2; redf[w*512 + lane*4 + 3] = p3;
      if (lane == 0) lred[w] = l;
      __syncthreads();
      if (tid < 256){
        float s4 = 0.f;
        #pragma unroll
        for (int ww = 0; ww < 8; ww++) s4 += redf[ww*512 + tid];
        atomicAdd(&ca_np[myb*256 + tid], s4);
      }
      if (tid == 0){
        float ls = 0.f;
        #pragma unroll
        for (int ww = 0; ww < 8; ww++) ls += lred[ww];
        atomicAdd(&la_np[myb], ls);
      }
    }
    gbar(ctr, &gen);  // SYNC3: context accumulated
  }
}

// ---------------------------------------------------------------------------
extern "C" void kernel_launch(void* const* d_in, const int* in_sizes, int n_in,
                              void* d_out, int out_size, void* d_ws, size_t ws_size,
                              hipStream_t stream){
  const float* enc    = (const float*)d_in[0];
  const float* embW   = (const float*)d_in[1];
  const float* W_ih1  = (const float*)d_in[2];
  const float* b_ih1  = (const float*)d_in[3];
  const float* W_hh1  = (const float*)d_in[4];
  const float* b_hh1  = (const float*)d_in[5];
  const float* W_ih2  = (const float*)d_in[6];
  const float* b_ih2  = (const float*)d_in[7];
  const float* W_hh2  = (const float*)d_in[8];
  const float* b_hh2  = (const float*)d_in[9];
  const float* Wk     = (const float*)d_in[10];
  const float* bk     = (const float*)d_in[11];
  const float* Wv     = (const float*)d_in[12];
  const float* bv     = (const float*)d_in[13];
  const float* Wq     = (const float*)d_in[14];
  const float* bq     = (const float*)d_in[15];
  const float* char_b = (const float*)d_in[16];
  const int*   lens   = (const int*)d_in[17];
  const int*   y      = (const int*)d_in[18];

  char* ws = (char*)d_ws;
  unsigned short* kvp  = (unsigned short*)(ws + 0);          // 52,428,800 B
  float* keybias       = (float*)(ws + 52428800);            //    204,800
  unsigned short* Bmat = (unsigned short*)(ws + 52633600);   //    524,288
  float* bvec          = (float*)(ws + 53157888);            //      2,048
  float* wkb           = (float*)(ws + 53159936);            //      2,048
  float* cb0           = (float*)(ws + 53161984);            //      1,024
  float* xh            = (float*)(ws + 53163008);            //    655,360
  float* ctxacc        = (float*)(ws + 53818368);            //    131,072
  float* lacc          = (float*)(ws + 53949440);            //      1,024
  float* h2buf         = (float*)(ws + 53950464);            //    131,072
  float* c1            = (float*)(ws + 54081536);            //    131,072
  float* c2            = (float*)(ws + 54212608);            //     65,536
  float* esc           = (float*)(ws + 54278144);            //      4,096
  unsigned int* ctr    = (unsigned int*)(ws + 54282240);     //      1,024 (256 uints)
  float* out = (float*)d_out;

  k_prepw<<<512, 256, 0, stream>>>(Wk, Wq, Wv, bk, bq, bv, Bmat, bvec, wkb, cb0);
  k_keybias<<<6400, 512, 0, stream>>>(enc, wkb, cb0, keybias);
  k_init<<<64, 256, 0, stream>>>(enc, Wk, bk, embW, xh, ctxacc, lacc, c1, c2, h2buf, ctr);
  k_gemm<<<6400, 256, 0, stream>>>(enc, Bmat, bvec, kvp);
  k_decode<<<256, 512, 0, stream>>>(W_ih1, b_ih1, W_hh1, b_hh1, W_ih2, b_ih2, W_hh2, b_hh2,
                                    embW, char_b, lens, y, kvp, keybias,
                                    xh, ctxacc, lacc, h2buf, c1, c2, esc, ctr, out);
}

// Round 4
// 22882.722 us; speedup vs baseline: 3.8483x; 1.3574x over previous
//
#include <hip/hip_runtime.h>

typedef float f32x4 __attribute__((ext_vector_type(4)));
typedef short s16x8 __attribute__((ext_vector_type(8)));

#define MINI(a,b) ((a)<(b)?(a):(b))
#define MAXI(a,b) ((a)>(b)?(a):(b))

static __device__ __forceinline__ float bf2f(unsigned short u){
  union { unsigned int i; float f; } x; x.i = ((unsigned int)u) << 16; return x.f;
}
static __device__ __forceinline__ unsigned short f2bf(float f){
  union { float f; unsigned int i; } x; x.f = f;
  return (unsigned short)((x.i + 0x7fffu + ((x.i >> 16) & 1u)) >> 16);
}
static __device__ __forceinline__ float sigm(float x){ return 1.f / (1.f + __expf(-x)); }
static __device__ __forceinline__ float tanhf_(float x){ return 1.f - 2.f / (1.f + __expf(2.f * x)); }

// --- per-access agent coherence (sc1 load/store, NO cache-wide inv/wb ops) ---
static __device__ __forceinline__ float ald1(const float* p){
  return __hip_atomic_load(p, __ATOMIC_RELAXED, __HIP_MEMORY_SCOPE_AGENT);
}
static __device__ __forceinline__ void ast1(float* p, float v){
  __hip_atomic_store(p, v, __ATOMIC_RELAXED, __HIP_MEMORY_SCOPE_AGENT);
}
static __device__ __forceinline__ float2 ald2(const float* p){
  unsigned long long u = __hip_atomic_load((const unsigned long long*)p,
                          __ATOMIC_RELAXED, __HIP_MEMORY_SCOPE_AGENT);
  union { unsigned long long u; float2 f; } c; c.u = u; return c.f;
}
static __device__ __forceinline__ void ast2(float* p, float a, float b){
  union { unsigned long long u; float f[2]; } c; c.f[0] = a; c.f[1] = b;
  __hip_atomic_store((unsigned long long*)p, c.u, __ATOMIC_RELAXED, __HIP_MEMORY_SCOPE_AGENT);
}
static __device__ __forceinline__ void aadd(float* p, float v){
  __hip_atomic_fetch_add(p, v, __ATOMIC_RELAXED, __HIP_MEMORY_SCOPE_AGENT);
}

// ---------------------------------------------------------------------------
// K1: fold Wq into key projection.  Bmat[k][n] (bf16): n<256 -> scale*Wk@Wq^T,
// n>=256 -> Wv.  bvec[n]: n<256 -> scale*bk@Wq^T, else bv.  wkb[k]=scale*Wk@bq.
// ---------------------------------------------------------------------------
__global__ void k_prepw(const float* Wk, const float* Wq, const float* Wv,
                        const float* bk, const float* bq, const float* bv,
                        unsigned short* Bm, float* bvec, float* wkb, float* cb0){
  const int k = blockIdx.x;     // 512 blocks
  const int t = threadIdx.x;    // 256 threads
  const float scale = 0.0625f;  // 1/sqrt(256)
  float acc = 0.f;
  for (int p = 0; p < 256; p++) acc += Wk[k*256+p] * Wq[t*256+p];
  Bm[(size_t)k*512 + t]       = f2bf(acc * scale);
  Bm[(size_t)k*512 + 256 + t] = f2bf(Wv[k*256+t]);
  __shared__ float red[256];
  red[t] = Wk[k*256+t] * bq[t];
  __syncthreads();
  for (int o = 128; o > 0; o >>= 1){ if (t < o) red[t] += red[t+o]; __syncthreads(); }
  if (t == 0) wkb[k] = red[0] * scale;
  if (k == 0){
    float a2 = 0.f;
    for (int p = 0; p < 256; p++) a2 += bk[p] * Wq[t*256+p];
    bvec[t] = a2 * scale;
    bvec[256+t] = bv[t];
    __syncthreads();
    red[t] = bk[t] * bq[t];
    __syncthreads();
    for (int o = 128; o > 0; o >>= 1){ if (t < o) red[t] += red[t+o]; __syncthreads(); }
    if (t == 0) *cb0 = red[0] * scale;
  }
}

// ---------------------------------------------------------------------------
// K2: keybias[m] = enc[m] . wkb + cb0
// ---------------------------------------------------------------------------
__global__ void k_keybias(const float* enc, const float* wkb, const float* cb0,
                          float* keybias){
  const int m = blockIdx.x*8 + (threadIdx.x >> 6);
  const int lane = threadIdx.x & 63;
  float p = 0.f;
  #pragma unroll
  for (int j = 0; j < 8; j++){ int k = lane + 64*j; p += enc[(size_t)m*512 + k] * wkb[k]; }
  #pragma unroll
  for (int o = 1; o < 64; o <<= 1) p += __shfl_xor(p, o, 64);
  if (lane == 0) keybias[m] = p + *cb0;
}

// ---------------------------------------------------------------------------
// K3: state init. ctx0 = key_proj[:,0,:] f32 exact, l=1, zero h1/c1/c2/h2/ctrs.
// ---------------------------------------------------------------------------
__global__ void k_init(const float* enc, const float* Wk, const float* bk,
                       float* h1b, float* ctxacc, float* lacc,
                       float* c1p, float* c2p, float* h2buf, unsigned int* ctr){
  const int b = blockIdx.x, t = threadIdx.x;  // 64 x 256
  float acc = bk[t];
  const float* er = enc + (size_t)b*800*512;
  for (int k = 0; k < 512; k++) acc += er[k] * Wk[(size_t)k*256 + t];
  ctxacc[b*256 + t] = acc;
  if (t == 0) lacc[b] = 1.f;
  for (int e = t; e < 512; e += 256) h1b[b*512 + e] = 0.f;
  for (int e = t; e < 512; e += 256) c1p[b*512 + e] = 0.f;  // flat zero (layout-agnostic)
  c2p[b*256 + t] = 0.f;
  h2buf[b*256 + t] = 0.f;
  if (b == 0) ctr[t] = 0u;
}

// ---------------------------------------------------------------------------
// K4: MFMA bf16 GEMM; epilogue scatters to keyT[b][k][s] and val[b][s][d].
// ---------------------------------------------------------------------------
__global__ __launch_bounds__(256) void k_gemm(const float* enc, const unsigned short* Bm,
                                              const float* bvec,
                                              unsigned short* kT, unsigned short* vl){
  __shared__ unsigned short Al[64][40];
  __shared__ unsigned short Bl[64][40];
  const int tid = threadIdx.x, w = tid >> 6, lane = tid & 63;
  const int M0 = (blockIdx.x >> 3) * 64;
  const int N0 = (blockIdx.x & 7) * 64;
  f32x4 acc[4] = {};
  const int mrow = w*16 + (lane & 15);
  const int koff = (lane >> 4) * 8;
  for (int k0 = 0; k0 < 512; k0 += 32){
    #pragma unroll
    for (int it = 0; it < 2; it++){
      int row = (tid >> 3) + it*32, kq = (tid & 7) * 4;
      float4 v = *(const float4*)(enc + (size_t)(M0+row)*512 + k0 + kq);
      Al[row][kq+0] = f2bf(v.x); Al[row][kq+1] = f2bf(v.y);
      Al[row][kq+2] = f2bf(v.z); Al[row][kq+3] = f2bf(v.w);
    }
    #pragma unroll
    for (int i = 0; i < 8; i++){
      int flat = tid*8 + i, kk = flat >> 6, n = flat & 63;
      Bl[n][kk] = Bm[(size_t)(k0+kk)*512 + N0 + n];
    }
    __syncthreads();
    s16x8 a = *(const s16x8*)&Al[mrow][koff];
    #pragma unroll
    for (int i = 0; i < 4; i++){
      s16x8 bb = *(const s16x8*)&Bl[i*16 + (lane & 15)][koff];
      acc[i] = __builtin_amdgcn_mfma_f32_16x16x32_bf16(a, bb, acc[i], 0, 0, 0);
    }
    __syncthreads();
  }
  #pragma unroll
  for (int i = 0; i < 4; i++){
    int n = N0 + i*16 + (lane & 15);
    float bb = bvec[n];
    #pragma unroll
    for (int r = 0; r < 4; r++){
      int m = M0 + w*16 + (lane >> 4)*4 + r;
      int b = m / 800, s = m - b*800;
      unsigned short hv = f2bf(acc[i][r] + bb);
      if (n < 256) kT[(size_t)b*204800 + (size_t)n*800 + s] = hv;
      else         vl[(size_t)b*204800 + (size_t)s*256 + (n-256)] = hv;
    }
  }
}

// ---------------------------------------------------------------------------
// Grid barrier: NO fences, NO cache-wide ops. __syncthreads drains vmcnt(0)
// (sc1 write-through stores then globally visible); relaxed add + relaxed poll.
// ---------------------------------------------------------------------------
static __device__ __forceinline__ void gbar(unsigned int* ctrs, unsigned int* gen){
  __syncthreads();
  if (threadIdx.x == 0){
    *gen += 256u;
    __hip_atomic_fetch_add(&ctrs[(blockIdx.x & 7) * 32], 1u,
                           __ATOMIC_RELAXED, __HIP_MEMORY_SCOPE_AGENT);
    const unsigned int target = *gen;
    for (;;){
      unsigned int s = 0;
      #pragma unroll
      for (int i = 0; i < 8; i++)
        s += __hip_atomic_load(&ctrs[i * 32], __ATOMIC_RELAXED, __HIP_MEMORY_SCOPE_AGENT);
      if (s >= target) break;
      __builtin_amdgcn_s_sleep(1);
    }
  }
  __syncthreads();
}

// plain-cached x (read-only source), LDS weights
static __device__ __forceinline__ void fmaP8(const float* xp, const float* wk, float* acc){
  float4 xv = *(const float4*)xp;
  float xs[4] = {xv.x, xv.y, xv.z, xv.w};
  #pragma unroll
  for (int kk = 0; kk < 4; kk++){
    const float* wr = wk + kk*8;
    #pragma unroll
    for (int c = 0; c < 8; c++) acc[c] += xs[kk]*wr[c];
  }
}
// agent-coherent x
static __device__ __forceinline__ void fmaA8(const float* xp, const float* wk, float* acc){
  float2 xa = ald2(xp), xb = ald2(xp+2);
  float xs[4] = {xa.x, xa.y, xb.x, xb.y};
  #pragma unroll
  for (int kk = 0; kk < 4; kk++){
    const float* wr = wk + kk*8;
    #pragma unroll
    for (int c = 0; c < 8; c++) acc[c] += xs[kk]*wr[c];
  }
}
static __device__ __forceinline__ void fmaA4(const float* xp, const float* wk, float* acc){
  float2 xa = ald2(xp), xb = ald2(xp+2);
  float xs[4] = {xa.x, xa.y, xb.x, xb.y};
  #pragma unroll
  for (int kk = 0; kk < 4; kk++){
    const float* wr = wk + kk*4;
    #pragma unroll
    for (int c = 0; c < 4; c++) acc[c] += xs[kk]*wr[c];
  }
}

__global__ __launch_bounds__(512) void k_decode(
    const float* W_ih1, const float* b_ih1, const float* W_hh1, const float* b_hh1,
    const float* W_ih2, const float* b_ih2, const float* W_hh2, const float* b_hh2,
    const float* embW, const float* char_b, const int* lens, const int* y,
    const unsigned short* kT, const unsigned short* vl, const float* keybias,
    float* h1b, float* ctxacc, float* lacc, float* h2buf, float* c1p, float* c2p,
    float* esc, unsigned int* ctr, float* out)
{
  __shared__ float W1s[1280][8];
  __shared__ float W2s[768][4];
  __shared__ float b1s[8];
  __shared__ float b2s[4];
  __shared__ float embrow[512];
  __shared__ float chb;
  __shared__ float redA[8][8][64];
  __shared__ float g1s[8][64];
  __shared__ float part[2][256];   // P3 score partials, reused as val partials
  __shared__ float e_l[256];
  __shared__ float h2loc[256];

  const int bi = blockIdx.x;
  const int tid = threadIdx.x;
  const int w = tid >> 6;
  const int lane = tid & 63;

  for (int idx = tid; idx < 1280*8; idx += 512){
    int k = idx >> 3, c = idx & 7;
    int col = ((c >> 1) << 9) + 2*bi + (c & 1);
    W1s[k][c] = (k < 768) ? W_ih1[(size_t)k*2048 + col] : W_hh1[(size_t)(k-768)*2048 + col];
  }
  for (int idx = tid; idx < 768*4; idx += 512){
    int k = idx >> 2, c = idx & 3;
    int col = (c << 8) + bi;
    W2s[k][c] = (k < 512) ? W_ih2[(size_t)k*1024 + col] : W_hh2[(size_t)(k-512)*1024 + col];
  }
  if (tid < 8){ int col = ((tid >> 1) << 9) + 2*bi + (tid & 1); b1s[tid] = b_ih1[col] + b_hh1[col]; }
  if (tid >= 8 && tid < 12){ int c = tid-8; int col = (c << 8) + bi; b2s[c] = b_ih2[col] + b_hh2[col]; }
  if (bi >= 192 && bi < 222){
    embrow[tid] = embW[(bi-192)*512 + tid];
    if (tid == 0) chb = char_b[bi-192];
  }
  __syncthreads();

  unsigned int gen = 0;
  const int myb = bi & 63;   // attention batch
  const int sc  = bi >> 6;   // attention s-quarter
  const int mylen = lens[myb];
  const int sbase = sc * 200;

  float* preds = out;            // [64][250][30]
  float* plot  = out + 480000;   // [800][250]

  for (int t = 0; t <= 250; ++t){
    const int p  = t & 1;
    const int np = 1 - p;
    const float* h1_p  = h1b + p*(64*512);
    float*       h1_np = h1b + np*(64*512);
    const float* ca_p  = ctxacc + p*(64*256);
    float*       ca_np = ctxacc + np*(64*256);
    const float* la_p  = lacc + p*64;
    float*       la_np = lacc + np*64;
    const float* h2_p  = h2buf + p*(64*256);
    float*       h2_np = h2buf + np*(64*256);

    // ---------------- Phase 1: gates1 ----------------
    if (t < 250){
      float acc[8]  = {0.f,0.f,0.f,0.f,0.f,0.f,0.f,0.f};
      float accB[8] = {0.f,0.f,0.f,0.f,0.f,0.f,0.f,0.f};
      const int b = lane;
      const int tok = (t == 0) ? 0 : y[b*250 + (t-1)];
      const float* erow = embW + (size_t)tok*512;          // plain cached (RO)
      const float* crow = ca_p + b*256 - 512;
      const float* hrow = h1_p + b*512 - 768;
      const int k0 = w*160, k1 = k0 + 160;
      const int a1 = MINI(k1, 512);
      for (int k = k0; k < a1; k += 4)  fmaP8(erow + k, &W1s[k][0], acc);
      const int bb0 = MAXI(k0, 512), bb1 = MINI(k1, 768);
      for (int k = bb0; k < bb1; k += 4) fmaA8(crow + k, &W1s[k][0], accB);
      const int cc0 = MAXI(k0, 768);
      for (int k = cc0; k < k1; k += 4) fmaA8(hrow + k, &W1s[k][0], acc);
      const float rl = 1.f / ald1(&la_p[b]);
      #pragma unroll
      for (int c = 0; c < 8; c++) redA[w][c][b] = acc[c] + accB[c]*rl;
    }
    __syncthreads();
    if (t < 250){
      { int c = tid >> 6, b = tid & 63;
        float g = b1s[c];
        #pragma unroll
        for (int ww = 0; ww < 8; ww++) g += redA[ww][c][b];
        g1s[c][b] = g;
      }
      __syncthreads();
      if (w == 0){   // LSTM1 cell for dims 2bi, 2bi+1
        int b = lane;
        float cn0, cn1;
        { float gi=g1s[0][b], gf=g1s[2][b], gg=g1s[4][b], go=g1s[6][b];
          float co = c1p[bi*128 + b*2];
          cn0 = sigm(gf)*co + sigm(gi)*tanhf_(gg);
          c1p[bi*128 + b*2] = cn0; cn0 = sigm(go)*tanhf_(cn0); }
        { float gi=g1s[1][b], gf=g1s[3][b], gg=g1s[5][b], go=g1s[7][b];
          float co = c1p[bi*128 + b*2 + 1];
          cn1 = sigm(gf)*co + sigm(gi)*tanhf_(gg);
          c1p[bi*128 + b*2 + 1] = cn1; cn1 = sigm(go)*tanhf_(cn1); }
        ast2(&h1_np[b*512 + 2*bi], cn0, cn1);
      }
    }
    __syncthreads();
    // ---------------- logits / plot for step t-1 (blocks 192..253) ----------------
    if (t > 0){
      if (bi >= 192 && bi < 222){
        int b3 = tid & 63, ch = tid >> 6;
        const float* base = (ch < 4) ? (h2_p + b3*256 + ch*64)
                                     : (ca_p + b3*256 + (ch-4)*64);
        const float* er = &embrow[(ch < 4) ? ch*64 : 256 + (ch-4)*64];
        float pc = 0.f;
        #pragma unroll 8
        for (int e = 0; e < 64; e += 2){
          float2 a = ald2(base + e);
          pc += a.x*er[e] + a.y*er[e+1];
        }
        if (ch >= 4) pc *= 1.f / ald1(&la_p[b3]);
        g1s[ch][b3] = pc;
      }
      __syncthreads();
      if (bi >= 192 && bi < 222 && tid < 64){
        float s2 = chb;
        #pragma unroll
        for (int ch = 0; ch < 8; ch++) s2 += g1s[ch][tid];
        preds[tid*7500 + (t-1)*30 + (bi-192)] = s2;
      } else if (bi >= 222 && bi < 254 && tid < 25){
        int s3 = (bi-222)*25 + tid;
        plot[(size_t)s3*250 + (t-1)] = ald1(&esc[s3]) * (1.f / ald1(&la_p[0]));
      }
    }
    if (t == 250) break;
    gbar(ctr, &gen);  // SYNC1: h1 ready

    // ---------------- Phase 2: gates2 + LSTM2 + housekeeping ----------------
    {
      float acc2[4] = {0.f,0.f,0.f,0.f};
      const int b = lane;
      const float* h1r = h1_np + b*512;
      const float* h2r = h2_p + b*256 - 512;
      const int k0 = w*96, k1 = k0 + 96;
      const int a1 = MINI(k1, 512);
      for (int k = k0; k < a1; k += 4) fmaA4(h1r + k, &W2s[k][0], acc2);
      const int bb0 = MAXI(k0, 512);
      for (int k = bb0; k < k1; k += 4) fmaA4(h2r + k, &W2s[k][0], acc2);
      #pragma unroll
      for (int c = 0; c < 4; c++) redA[w][c][b] = acc2[c];
    }
    __syncthreads();
    if (tid < 256){
      int c = tid >> 6, b = tid & 63;
      float g = b2s[c];
      #pragma unroll
      for (int ww = 0; ww < 8; ww++) g += redA[ww][c][b];
      g1s[c][b] = g;
    }
    __syncthreads();
    if (w == 0){
      int b = lane;
      float gi = g1s[0][b], gf = g1s[1][b], gg = g1s[2][b], go = g1s[3][b];
      float cold = c2p[bi*64 + b];
      float cn = sigm(gf)*cold + sigm(gi)*tanhf_(gg);
      c2p[bi*64 + b] = cn;
      ast1(&h2_np[b*256 + bi], sigm(go)*tanhf_(cn));
    }
    if (tid >= 64 && tid < 96) ast2(&ca_np[bi*64 + 2*(tid-64)], 0.f, 0.f);
    if (tid == 96 && bi < 64) ast1(&la_np[bi], 0.f);
    gbar(ctr, &gen);  // SYNC2: h2 ready, accumulators zeroed

    // ---------------- Phase 3: attention (quarter sbase..sbase+200) ----------------
    {
      if (tid < 128){ float2 hv = ald2(&h2_np[myb*256 + 2*tid]);
                      h2loc[2*tid] = hv.x; h2loc[2*tid+1] = hv.y; }
      __syncthreads();
      const int qlen = MINI(200, MAXI(0, mylen - sbase));
      const int srow = tid & 255, kh = tid >> 8;
      if (srow < qlen){
        const unsigned short* kp = kT + (size_t)myb*204800 + (size_t)(kh*128)*800 + sbase + srow;
        const float* hl = &h2loc[kh*128];
        float pacc = 0.f;
        #pragma unroll 4
        for (int k = 0; k < 128; k++){ pacc += bf2f(*kp)*hl[k]; kp += 800; }
        part[kh][srow] = pacc;
      }
      __syncthreads();
      if (tid < 256){
        float e = 0.f;
        if (tid < qlen) e = __expf(part[0][tid] + part[1][tid] + keybias[myb*800 + sbase + tid]);
        e_l[tid] = e;
        if (myb == 0 && tid < 200) ast1(&esc[sbase + tid], e);
      }
      __syncthreads();
      if (w == 0){
        float s4 = e_l[lane] + e_l[lane+64] + e_l[lane+128] + e_l[lane+192];
        #pragma unroll
        for (int o = 1; o < 64; o <<= 1) s4 += __shfl_xor(s4, o, 64);
        if (lane == 0) aadd(&la_np[myb], s4);
      }
      {
        const int d = tid & 255, rh = tid >> 8;
        const int j0 = rh*100, j1 = MINI(j0+100, qlen);
        float a = 0.f;
        const unsigned short* vp = vl + (size_t)myb*204800 + (size_t)(sbase+j0)*256 + d;
        #pragma unroll 4
        for (int j = j0; j < j1; j++){ a += e_l[j]*bf2f(*vp); vp += 256; }
        part[rh][d] = a;   // reuse as val partials (score reads done)
      }
      __syncthreads();
      if (tid < 256) aadd(&ca_np[myb*256 + tid], part[0][tid] + part[1][tid]);
    }
    gbar(ctr, &gen);  // SYNC3: context accumulated
  }
}

// ---------------------------------------------------------------------------
extern "C" void kernel_launch(void* const* d_in, const int* in_sizes, int n_in,
                              void* d_out, int out_size, void* d_ws, size_t ws_size,
                              hipStream_t stream){
  const float* enc    = (const float*)d_in[0];
  const float* embW   = (const float*)d_in[1];
  const float* W_ih1  = (const float*)d_in[2];
  const float* b_ih1  = (const float*)d_in[3];
  const float* W_hh1  = (const float*)d_in[4];
  const float* b_hh1  = (const float*)d_in[5];
  const float* W_ih2  = (const float*)d_in[6];
  const float* b_ih2  = (const float*)d_in[7];
  const float* W_hh2  = (const float*)d_in[8];
  const float* b_hh2  = (const float*)d_in[9];
  const float* Wk     = (const float*)d_in[10];
  const float* bk     = (const float*)d_in[11];
  const float* Wv     = (const float*)d_in[12];
  const float* bv     = (const float*)d_in[13];
  const float* Wq     = (const float*)d_in[14];
  const float* bq     = (const float*)d_in[15];
  const float* char_b = (const float*)d_in[16];
  const int*   lens   = (const int*)d_in[17];
  const int*   y      = (const int*)d_in[18];

  char* ws = (char*)d_ws;
  unsigned short* kT   = (unsigned short*)(ws + 0);          // 26,214,400
  unsigned short* vlp  = (unsigned short*)(ws + 26214400);   // 26,214,400
  float* keybias       = (float*)(ws + 52428800);            //    204,800
  unsigned short* Bmat = (unsigned short*)(ws + 52633600);   //    524,288
  float* bvec          = (float*)(ws + 53157888);            //      2,048
  float* wkb           = (float*)(ws + 53159936);            //      2,048
  float* cb0           = (float*)(ws + 53161984);            //      1,024
  float* h1b           = (float*)(ws + 53163008);            //    262,144 (2 bufs)
  float* ctxacc        = (float*)(ws + 53425152);            //    131,072
  float* lacc          = (float*)(ws + 53556224);            //      1,024
  float* h2buf         = (float*)(ws + 53557248);            //    131,072
  float* c1p           = (float*)(ws + 53688320);            //    131,072
  float* c2p           = (float*)(ws + 53819392);            //     65,536
  float* esc           = (float*)(ws + 53884928);            //      4,096
  unsigned int* ctr    = (unsigned int*)(ws + 53889024);     //      1,024
  float* out = (float*)d_out;

  k_prepw<<<512, 256, 0, stream>>>(Wk, Wq, Wv, bk, bq, bv, Bmat, bvec, wkb, cb0);
  k_keybias<<<6400, 512, 0, stream>>>(enc, wkb, cb0, keybias);
  k_init<<<64, 256, 0, stream>>>(enc, Wk, bk, h1b, ctxacc, lacc, c1p, c2p, h2buf, ctr);
  k_gemm<<<6400, 256, 0, stream>>>(enc, Bmat, bvec, kT, vlp);
  k_decode<<<256, 512, 0, stream>>>(W_ih1, b_ih1, W_hh1, b_hh1, W_ih2, b_ih2, W_hh2, b_hh2,
                                    embW, char_b, lens, y, kT, vlp, keybias,
                                    h1b, ctxacc, lacc, h2buf, c1p, c2p, esc, ctr, out);
}